// Round 7
// baseline (707.401 us; speedup 1.0000x reference)
//
#include <hip/hip_runtime.h>
#include <hip/hip_bf16.h>
#include <hip/hip_fp16.h>

// Problem constants
#define NB 8
#define NT 1024
#define MD 1024
#define SD 256
#define NSTATES 16
#define NTOK (NB*NT)            // 8192
#define OUT_MAIN (NTOK*MD)      // 8388608

typedef __attribute__((ext_vector_type(8))) short bf16x8;
typedef __attribute__((ext_vector_type(4))) float f32x4;

static __device__ __forceinline__ unsigned short f32_to_bf16_bits(float f) {
    union { float f; unsigned u; } v; v.f = f;
    unsigned r = v.u + 0x7FFFu + ((v.u >> 16) & 1u);
    return (unsigned short)(r >> 16);
}

// i8 dot4 with VGPR-class operands
#define DOT4(acc, h, w) asm("v_dot4_i32_i8 %0, %1, %2, %0" : "+v"(acc) : "v"(h), "v"(w))

static __device__ __forceinline__ float fast_exp2(float x) {
#if __has_builtin(__builtin_amdgcn_exp2f)
    return __builtin_amdgcn_exp2f(x);
#else
    return exp2f(x);
#endif
}
static __device__ __forceinline__ float fast_rcp(float x) {
#if __has_builtin(__builtin_amdgcn_rcpf)
    return __builtin_amdgcn_rcpf(x);
#else
    return 1.f / x;
#endif
}

// int butterfly-add over 8 consecutive lanes: xor1, xor2, mirror-within-8
static __device__ __forceinline__ int bsum8(int v) {
    v += __builtin_amdgcn_update_dpp(0, v, 0xB1,  0xF, 0xF, true);  // quad_perm [1,0,3,2]
    v += __builtin_amdgcn_update_dpp(0, v, 0x4E,  0xF, 0xF, true);  // quad_perm [2,3,0,1]
    v += __builtin_amdgcn_update_dpp(0, v, 0x141, 0xF, 0xF, true);  // row_half_mirror
    return v;
}

#define STEP_BARRIER() do { \
    asm volatile("s_waitcnt lgkmcnt(0)" ::: "memory"); \
    __builtin_amdgcn_s_barrier(); \
    asm volatile("" ::: "memory"); } while (0)

// ---------------------------------------------------------------------------
// K1: out = base (exact f32 copy), zero accumulators (ent_sum f32, count u32)
__global__ void k_copy_zero(const float4* __restrict__ base, float4* __restrict__ out,
                            float* __restrict__ accums) {
    unsigned i = blockIdx.x * 256u + threadIdx.x;
    const unsigned STRIDE = 524288u; // total float4 = 2097152
#pragma unroll
    for (int q = 0; q < 4; q++) out[i + q * STRIDE] = base[i + q * STRIDE];
    if (i == 0u) { accums[0] = 0.f; ((unsigned*)accums)[1] = 0u; }
}

// ---------------------------------------------------------------------------
// K2: prep weights + active list (identical layout to round-4/6).
__global__ void k_prep(const float* __restrict__ Wsi, const float* __restrict__ Wgi,
                       const float* __restrict__ Wsh, const float* __restrict__ Wgh,
                       const int* __restrict__ ids, const int* __restrict__ t2s,
                       unsigned short* __restrict__ Bt, unsigned* __restrict__ Wpack,
                       unsigned* __restrict__ list, unsigned* __restrict__ countp) {
    unsigned i = blockIdx.x * 256u + threadIdx.x;
    if (i < 524288u) {
        unsigned n = i >> 10, k = i & 1023u;
        float v = (n < 256u) ? Wsi[k * 256u + n] : Wgi[k * 256u + (n - 256u)];
        Bt[i] = f32_to_bf16_bits(v);
    } else if (i < 557056u) {
        unsigned w = i - 524288u;            // 0..32767
        unsigned e   = w & 3u;
        unsigned tid = (w >> 2) & 511u;
        unsigned i4  = w >> 11;              // 0..15
        unsigned q   = i4 & 1u;
        unsigned a   = i4 >> 1;              // 0..7
        unsigned lane = tid & 63u, wv = tid >> 6;
        unsigned ko = lane & 7u, jg = lane >> 3;
        unsigned G  = wv * 8u + jg;
        unsigned j  = 4u * G + (a & 3u);
        unsigned c  = (q ^ (ko & 1u)) & 1u;
        unsigned k0 = ko * 32u + c * 16u + e * 4u;
        const float* W = (a >> 2) ? Wgh : Wsh;
        unsigned word = 0u;
#pragma unroll
        for (int r = 0; r < 4; r++) {
            float wf = W[(k0 + (unsigned)r) * 256u + j];
            int iv = (int)rintf(wf * 1270.f);
            iv = iv > 127 ? 127 : (iv < -127 ? -127 : iv);
            word |= ((unsigned)iv & 0xFFu) << (8 * r);
        }
        Wpack[w] = word;
    } else if (i < 565248u) {
        unsigned tok = i - 557056u;
        int slot = t2s[ids[tok]];
        if (slot >= 0) {
            unsigned pos = atomicAdd(countp, 1u);
            list[pos] = (tok << 6) | (unsigned)slot;
        }
    }
}

// ---------------------------------------------------------------------------
// K3: XW[8192][512] f32 = bf16(base) @ [Wsi|Wgi]  (unchanged)
__launch_bounds__(512, 1)
__global__ void k_gemm(const float* __restrict__ A, const unsigned short* __restrict__ Bt,
                       float* __restrict__ XW) {
    __shared__ __align__(16) unsigned short Abuf[128 * 40];
    __shared__ __align__(16) unsigned short Bbuf[256 * 40];
    const unsigned tid = threadIdx.x;
    const unsigned m0 = blockIdx.x * 128u;
    const unsigned n0 = blockIdx.y * 256u;
    const unsigned wave = tid >> 6, lane = tid & 63u;
    const unsigned wm = wave >> 2, wn = wave & 3u;
    const unsigned l15 = lane & 15u, kg = lane >> 4;
    const unsigned ar = tid >> 2;
    const unsigned ac = (tid & 3u) * 8u;

    f32x4 acc[4][4];
#pragma unroll
    for (int i = 0; i < 4; i++)
#pragma unroll
        for (int j = 0; j < 4; j++) acc[i][j] = (f32x4){0.f, 0.f, 0.f, 0.f};

    for (unsigned k0 = 0; k0 < 1024u; k0 += 32u) {
        {
            const float* src = A + (size_t)(m0 + ar) * 1024u + k0 + ac;
            float4 f0 = *(const float4*)src;
            float4 f1 = *(const float4*)(src + 4);
            unsigned short* dst = &Abuf[ar * 40u + ac];
            dst[0] = f32_to_bf16_bits(f0.x); dst[1] = f32_to_bf16_bits(f0.y);
            dst[2] = f32_to_bf16_bits(f0.z); dst[3] = f32_to_bf16_bits(f0.w);
            dst[4] = f32_to_bf16_bits(f1.x); dst[5] = f32_to_bf16_bits(f1.y);
            dst[6] = f32_to_bf16_bits(f1.z); dst[7] = f32_to_bf16_bits(f1.w);
        }
#pragma unroll
        for (int q = 0; q < 2; q++) {
            unsigned br = q * 128u + (tid >> 2);
            const unsigned short* src = Bt + (size_t)(n0 + br) * 1024u + k0 + ac;
            *(uint4*)&Bbuf[br * 40u + ac] = *(const uint4*)src;
        }
        __syncthreads();
        bf16x8 a[4], b[4];
#pragma unroll
        for (int i = 0; i < 4; i++)
            a[i] = *(const bf16x8*)&Abuf[(wm * 64u + i * 16u + l15) * 40u + kg * 8u];
#pragma unroll
        for (int j = 0; j < 4; j++)
            b[j] = *(const bf16x8*)&Bbuf[(wn * 64u + j * 16u + l15) * 40u + kg * 8u];
#pragma unroll
        for (int i = 0; i < 4; i++)
#pragma unroll
            for (int j = 0; j < 4; j++)
                acc[i][j] = __builtin_amdgcn_mfma_f32_16x16x32_bf16(a[i], b[j], acc[i][j], 0, 0, 0);
        __syncthreads();
    }
#pragma unroll
    for (int i = 0; i < 4; i++) {
        unsigned row_b = m0 + wm * 64u + i * 16u + kg * 4u;
#pragma unroll
        for (int j = 0; j < 4; j++) {
            unsigned col = n0 + wn * 64u + j * 16u + l15;
#pragma unroll
            for (int r = 0; r < 4; r++)
                XW[(size_t)(row_b + r) * 512u + col] = acc[i][j][r];
        }
    }
}

// ---------------------------------------------------------------------------
// K4: sequential GRU recurrence, v7 (int8 asm-dot4, 512 threads, slim regs).
// Change vs v6: NO xw register buffers (was 32 VGPRs) -> per-step 2 scalar
// prefetch loads (xw slice for (b,t) is contiguous: XW + (b*1024+t)*512).
// Total per-thread register demand ~105 < 128 so the allocator can keep the
// 64 weight dwords in arch VGPRs at its 4-waves/SIMD budget target (the
// r4/r5/r6 AGPR-homing happened when demand exceeded 128).
__launch_bounds__(512, 2)
__global__ void k_rec(const float* __restrict__ XW, const unsigned* __restrict__ Wpack,
                      float* __restrict__ prefix) {
    __shared__ __align__(16) unsigned char hB[2][256];
    const unsigned tid = threadIdx.x;
    const unsigned lane = tid & 63u, wv = tid >> 6;
    const unsigned ko = lane & 7u, jg = lane >> 3;
    const unsigned G = wv * 8u + jg;
    const unsigned jc = ko & 3u;
    const unsigned j = 4u * G + jc;
    const unsigned b = blockIdx.x;

    // register-resident weights: 16 uint4 = 64 dwords of packed i8
    uint4 w[8][2];
#pragma unroll
    for (int a = 0; a < 8; a++)
#pragma unroll
        for (int q = 0; q < 2; q++)
            w[a][q] = ((const uint4*)Wpack)[(a * 2 + q) * 512 + tid];

    if (tid < 128u) ((unsigned*)&hB[0][0])[tid] = 0u;   // zero both h buffers
    __syncthreads();

    // per-lane h read offsets (XOR order across the octet, matches Wpack)
    const unsigned c0 = ko & 1u;
    const unsigned off_q0 = ko * 32u + c0 * 16u;
    const unsigned off_q1 = ko * 32u + (c0 ^ 1u) * 16u;

    const float* xwj = XW + (size_t)b * (1024u * 512u) + j;
    float* pfb = prefix + (size_t)b * (1024u * 256u) + j;

    const float L2E = 1.4426950408889634f;
    const float DOT_SCALE = 6.2000124e-06f;   // 1/(127*1270)
    float hold = 0.f;

    float xws = xwj[0];
    float xwg = xwj[256];

    for (unsigned t = 0; t < 1024u; ++t) {
        // prefetch next step's xw (consumed ~1.5 steps later; compiler-managed waits)
        unsigned tn = (t + 1u < 1024u) ? (t + 1u) : 1023u;
        float xws_n = xwj[tn * 512u];
        float xwg_n = xwj[tn * 512u + 256u];

        const unsigned char* hRd = &hB[t & 1u][0];
        unsigned char* hWr = (unsigned char*)&hB[(t + 1u) & 1u][0];
        uint4 h0 = *(const uint4*)(hRd + off_q0);
        uint4 h1 = *(const uint4*)(hRd + off_q1);
        int a0 = 0, a1 = 0, a2 = 0, a3 = 0, a4 = 0, a5 = 0, a6 = 0, a7 = 0;
        DOT4(a0, h0.x, w[0][0].x); DOT4(a1, h0.x, w[1][0].x);
        DOT4(a2, h0.x, w[2][0].x); DOT4(a3, h0.x, w[3][0].x);
        DOT4(a4, h0.x, w[4][0].x); DOT4(a5, h0.x, w[5][0].x);
        DOT4(a6, h0.x, w[6][0].x); DOT4(a7, h0.x, w[7][0].x);
        DOT4(a0, h0.y, w[0][0].y); DOT4(a1, h0.y, w[1][0].y);
        DOT4(a2, h0.y, w[2][0].y); DOT4(a3, h0.y, w[3][0].y);
        DOT4(a4, h0.y, w[4][0].y); DOT4(a5, h0.y, w[5][0].y);
        DOT4(a6, h0.y, w[6][0].y); DOT4(a7, h0.y, w[7][0].y);
        DOT4(a0, h0.z, w[0][0].z); DOT4(a1, h0.z, w[1][0].z);
        DOT4(a2, h0.z, w[2][0].z); DOT4(a3, h0.z, w[3][0].z);
        DOT4(a4, h0.z, w[4][0].z); DOT4(a5, h0.z, w[5][0].z);
        DOT4(a6, h0.z, w[6][0].z); DOT4(a7, h0.z, w[7][0].z);
        DOT4(a0, h0.w, w[0][0].w); DOT4(a1, h0.w, w[1][0].w);
        DOT4(a2, h0.w, w[2][0].w); DOT4(a3, h0.w, w[3][0].w);
        DOT4(a4, h0.w, w[4][0].w); DOT4(a5, h0.w, w[5][0].w);
        DOT4(a6, h0.w, w[6][0].w); DOT4(a7, h0.w, w[7][0].w);
        DOT4(a0, h1.x, w[0][1].x); DOT4(a1, h1.x, w[1][1].x);
        DOT4(a2, h1.x, w[2][1].x); DOT4(a3, h1.x, w[3][1].x);
        DOT4(a4, h1.x, w[4][1].x); DOT4(a5, h1.x, w[5][1].x);
        DOT4(a6, h1.x, w[6][1].x); DOT4(a7, h1.x, w[7][1].x);
        DOT4(a0, h1.y, w[0][1].y); DOT4(a1, h1.y, w[1][1].y);
        DOT4(a2, h1.y, w[2][1].y); DOT4(a3, h1.y, w[3][1].y);
        DOT4(a4, h1.y, w[4][1].y); DOT4(a5, h1.y, w[5][1].y);
        DOT4(a6, h1.y, w[6][1].y); DOT4(a7, h1.y, w[7][1].y);
        DOT4(a0, h1.z, w[0][1].z); DOT4(a1, h1.z, w[1][1].z);
        DOT4(a2, h1.z, w[2][1].z); DOT4(a3, h1.z, w[3][1].z);
        DOT4(a4, h1.z, w[4][1].z); DOT4(a5, h1.z, w[5][1].z);
        DOT4(a6, h1.z, w[6][1].z); DOT4(a7, h1.z, w[7][1].z);
        DOT4(a0, h1.w, w[0][1].w); DOT4(a1, h1.w, w[1][1].w);
        DOT4(a2, h1.w, w[2][1].w); DOT4(a3, h1.w, w[3][1].w);
        DOT4(a4, h1.w, w[4][1].w); DOT4(a5, h1.w, w[5][1].w);
        DOT4(a6, h1.w, w[6][1].w); DOT4(a7, h1.w, w[7][1].w);
        a0 = bsum8(a0); a1 = bsum8(a1); a2 = bsum8(a2); a3 = bsum8(a3);
        a4 = bsum8(a4); a5 = bsum8(a5); a6 = bsum8(a6); a7 = bsum8(a7);
        int ts = (jc & 2u) ? ((jc & 1u) ? a3 : a2) : ((jc & 1u) ? a1 : a0);
        int tg = (jc & 2u) ? ((jc & 1u) ? a7 : a6) : ((jc & 1u) ? a5 : a4);
        float sv = fmaf((float)ts, DOT_SCALE, xws);
        float gv = fmaf((float)tg, DOT_SCALE, xwg);
        float gate = fast_rcp(1.f + fast_exp2(-gv * L2E));
        float prop = 1.f - 2.f * fast_rcp(1.f + fast_exp2(2.f * L2E * sv));
        float hnew = hold + gate * (prop - hold);
        if (ko < 4u) {
            pfb[(size_t)t * 256u] = hold;               // fire-and-forget store
            hWr[j] = (unsigned char)((unsigned)(int)rintf(hnew * 127.f) & 0xFFu);
        }
        hold = hnew;
        xws = xws_n; xwg = xwg_n;
        STEP_BARRIER();
    }
}

// ---------------------------------------------------------------------------
// K5: router + delta mix at active tokens only. grid-stride over device count.
__launch_bounds__(256, 1)
__global__ void k_router(const unsigned* __restrict__ list, const float* __restrict__ accums_ro,
                         const float* __restrict__ prefix, const float* __restrict__ base,
                         const float* __restrict__ Wrh, const float* __restrict__ Wro,
                         const float* __restrict__ delta, float* __restrict__ out,
                         float* __restrict__ ent_sum) {
    const unsigned cnt = ((const unsigned*)accums_ro)[1];
    __shared__ float f[1280];
    __shared__ float hid[256];
    __shared__ float pr[16];
    const unsigned tid = threadIdx.x;
    for (unsigned idx = blockIdx.x; idx < cnt; idx += gridDim.x) {
        unsigned e = list[idx];
        unsigned tok = e >> 6, slot = e & 63u;
        f[tid] = prefix[(size_t)tok * 256u + tid];
#pragma unroll
        for (int q = 0; q < 4; q++)
            f[256u + q * 256u + tid] = base[(size_t)tok * 1024u + q * 256u + tid];
        __syncthreads();
        float a = 0.f;
        for (unsigned k = 0; k < 1280u; k++) a += f[k] * Wrh[k * 256u + tid];
        hid[tid] = tanhf(a);
        __syncthreads();
        if (tid < 16u) {
            float l = 0.f;
            for (unsigned k = 0; k < 256u; k++) l += hid[k] * Wro[k * 16u + tid];
            pr[tid] = l;
        }
        __syncthreads();
        if (tid == 0u) {
            float m = pr[0];
#pragma unroll
            for (int n = 1; n < 16; n++) m = fmaxf(m, pr[n]);
            float es[16]; float ssum = 0.f;
#pragma unroll
            for (int n = 0; n < 16; n++) { es[n] = expf(pr[n] - m); ssum += es[n]; }
            float inv = 1.f / ssum, ent = 0.f;
#pragma unroll
            for (int n = 0; n < 16; n++) {
                float p = es[n] * inv;
                pr[n] = p;
                ent -= p * logf(fmaxf(p, 1e-8f));
            }
            atomicAdd(ent_sum, ent);
        }
        __syncthreads();
        {
            const float* dslot = delta + (size_t)slot * 16u * 1024u;
            unsigned d0 = tid * 4u;
            float4 m4 = {0.f, 0.f, 0.f, 0.f};
#pragma unroll
            for (int n = 0; n < 16; n++) {
                float p = pr[n];
                float4 dv = *(const float4*)(dslot + n * 1024u + d0);
                m4.x += p * dv.x; m4.y += p * dv.y; m4.z += p * dv.z; m4.w += p * dv.w;
            }
            float* op = out + (size_t)tok * 1024u + d0;
            float4 cur = *(const float4*)op;
            cur.x += 0.25f * m4.x; cur.y += 0.25f * m4.y;
            cur.z += 0.25f * m4.z; cur.w += 0.25f * m4.w;
            *(float4*)op = cur;
        }
        __syncthreads();
    }
}

// ---------------------------------------------------------------------------
// K6: scalars
__global__ void k_final(const float* __restrict__ accums, float* __restrict__ out) {
    float ent = accums[0];
    unsigned cnt = ((const unsigned*)accums)[1];
    out[OUT_MAIN]     = (cnt > 0u) ? ent / (float)cnt : 0.f;
    out[OUT_MAIN + 1] = (float)cnt / 8192.f;
}

// ---------------------------------------------------------------------------
extern "C" void kernel_launch(void* const* d_in, const int* in_sizes, int n_in,
                              void* d_out, int out_size, void* d_ws, size_t ws_size,
                              hipStream_t stream) {
    const int*   ids  = (const int*)d_in[0];
    const float* base = (const float*)d_in[1];
    const int*   t2s  = (const int*)d_in[2];
    const float* Wsi  = (const float*)d_in[3];
    const float* Wsh  = (const float*)d_in[4];
    const float* Wgi  = (const float*)d_in[5];
    const float* Wgh  = (const float*)d_in[6];
    const float* Wrh  = (const float*)d_in[7];
    const float* Wro  = (const float*)d_in[8];
    const float* delta = (const float*)d_in[9];
    float* out = (float*)d_out;

    char* ws = (char*)d_ws;
    float*          XW     = (float*)(ws);                      // 16,777,216 B
    float*          prefix = (float*)(ws + 16777216);           //  8,388,608 B
    unsigned short* Bt     = (unsigned short*)(ws + 25165824);  //  1,048,576 B
    unsigned*       Wpack  = (unsigned*)(ws + 26214400);        //    131,072 B
    unsigned*       list   = (unsigned*)(ws + 26345472);        //     32,768 B
    float*          accums = (float*)(ws + 26378240);           //          8 B

    hipLaunchKernelGGL(k_copy_zero, dim3(2048), dim3(256), 0, stream,
                       (const float4*)base, (float4*)out, accums);
    hipLaunchKernelGGL(k_prep, dim3(2208), dim3(256), 0, stream,
                       Wsi, Wgi, Wsh, Wgh, ids, t2s, Bt, Wpack, list,
                       (unsigned*)accums + 1);
    hipLaunchKernelGGL(k_gemm, dim3(64, 2), dim3(512), 0, stream, base, Bt, XW);
    hipLaunchKernelGGL(k_rec, dim3(8), dim3(512), 0, stream, XW, Wpack, prefix);
    hipLaunchKernelGGL(k_router, dim3(64), dim3(256), 0, stream,
                       list, accums, prefix, base, Wrh, Wro, delta, out, accums);
    hipLaunchKernelGGL(k_final, dim3(1), dim3(1), 0, stream, accums, out);
}